// Round 5
// baseline (664.506 us; speedup 1.0000x reference)
//
#include <hip/hip_runtime.h>
#include <hip/hip_cooperative_groups.h>

#define N_NODES 100000
#define N_EDGESV 1000000
#define N_REL 7
#define IN_CH 128
#define HID_CH 64
#define NBINS 800000          // (dst, rel) bins: key = d*8 + r
#define OFFM 0x0FFFFFFFu
#define NTILES 6250           // N_NODES / 16
#define NSB 196               // super-buckets: dst>>9 (512 nodes each)
#define SBCAP 8192            // mean 5102, sigma~71 -> +43 sigma margin
#define NBLK_A1 512
#define CHUNK 1954            // ceil(1e6 / 512)
#define XH_BLOCKS 2048
#define WB_BLOCKS 64
#define XH_TOTAL (N_NODES * IN_CH / 4)
#define MB 512                // mega-kernel blocks (2 per CU guaranteed)
#define MT 512                // mega-kernel threads

typedef _Float16 f16;
typedef __attribute__((ext_vector_type(8))) _Float16 f16x8;
typedef __attribute__((ext_vector_type(4))) _Float16 f16x4;
typedef __attribute__((ext_vector_type(4))) float f32x4;

// ===================================================================================
// ============================ MEGA COOPERATIVE KERNEL ==============================
// One dispatch; phases separated by grid.sync(). 512 blocks x 512 thr, 2 blocks/CU
// guaranteed (launch_bounds caps regs at 128; LDS 18.9KB). Phase bodies are the
// proven round-2/round-4 implementations re-strided for this geometry.
// ===================================================================================
__global__ __launch_bounds__(MT, 4)
void mega_kernel(const int* __restrict__ ei, const int* __restrict__ et,
                 const float* __restrict__ x, const float* __restrict__ W1,
                 const float* __restrict__ root1, const float* __restrict__ bias1,
                 const float* __restrict__ comp2, const float* __restrict__ basis2,
                 const float* __restrict__ root2, const float* __restrict__ bias2,
                 int* __restrict__ gcur, int2* __restrict__ btmp,
                 int* __restrict__ off2, int* __restrict__ packed1,
                 f16* __restrict__ xh, f16* __restrict__ wbt, f16* __restrict__ w2t,
                 f16* __restrict__ dense1, f16* __restrict__ h16,
                 float* __restrict__ msg2, float* __restrict__ out)
{
    cooperative_groups::grid_group grid = cooperative_groups::this_grid();
    __shared__ __align__(16) char smem[18944];
    const int tid = threadIdx.x;
    const int bid = blockIdx.x;
    const int gtid = bid * MT + tid;

    // ---------------- P0: zero gcur | off2[0] | xh | wbuild ----------------
    if (gtid < NSB) gcur[gtid] = 0;
    if (gtid == NSB) off2[0] = 0;
    for (int i = gtid; i < XH_TOTAL; i += MB * MT) {
        float4 v = ((const float4*)x)[i];
        f16x4 o = {(f16)v.x, (f16)v.y, (f16)v.z, (f16)v.w};
        *(f16x4*)(xh + (size_t)i * 4) = o;
    }
    // wbuild: permuted rows (round-1 verified): physical row p holds logical col
    // (p&~63)|perm(p&63), perm(l)=((l&15)>>2)*16+((l>>4)<<2)+(l&3)
    for (int idx = gtid; idx < 512 * 128; idx += MB * MT) {
        int p = idx >> 7, k = idx & 127;
        int lp = p & 63;
        int lc = ((lp & 15) >> 2) * 16 + ((lp >> 4) << 2) + (lp & 3);
        int col = (p & ~63) | lc;
        float v;
        if (col < 64) {
            v = root1[k * HID_CH + col];
        } else {
            int cc = col - 64, r = cc >> 6, inner = cc & 63, b = inner >> 4, j = inner & 15;
            int kb = k - b * 32;
            v = (kb >= 0 && kb < 32) ? W1[(((r * 4 + b) * 32) + kb) * 16 + j] : 0.f;
        }
        wbt[idx] = (f16)v;
    }
    for (int idx = gtid; idx < 16 * 64; idx += MB * MT) {
        int col = idx >> 6, k = idx & 63;
        float v;
        if (col < 14) {
            int r = col >> 1, oc = col & 1;
            v = 0.f;
            for (int b = 0; b < 4; ++b) v += comp2[r * 4 + b] * basis2[(b * 64 + k) * 2 + oc];
        } else {
            v = root2[k * 2 + (col - 14)];
        }
        w2t[idx] = (f16)v;
    }
    grid.sync();

    // ---------------- P1: passA1 (chunk = bid; 512 chunks exactly) ----------------
    {
        int2* ent  = (int2*)smem;            // 15632 B
        int* lhist = (int*)(smem + 15632);   // 784 B
        int* lcur  = (int*)(smem + 16416);
        int* gposl = (int*)(smem + 17200);
        const int cbase = bid * CHUNK;
        const int cnt = min(CHUNK, N_EDGESV - cbase);

        for (int i = tid; i < NSB; i += MT) { lhist[i] = 0; lcur[i] = 0; }
        __syncthreads();

        for (int i = tid; i < cnt; i += MT) {
            int e = cbase + i;
            int d = ei[N_EDGESV + e];
            int s = ei[e];
            int r = et[e];
            ent[i] = make_int2((d << 3) + r, (s * 1024 + 128 + r * 128) | (r << 28));
            atomicAdd(&lhist[d >> 9], 1);
        }
        __syncthreads();

        for (int b = tid; b < NSB; b += MT)
            gposl[b] = atomicAdd(&gcur[b], lhist[b]);
        __syncthreads();

        for (int i = tid; i < cnt; i += MT) {
            int2 en = ent[i];
            int b = en.x >> 12;
            int off = atomicAdd(&lcur[b], 1);
            int idx = gposl[b] + off;
            if (idx < SBCAP) btmp[(size_t)b * SBCAP + idx] = en;
        }
    }
    grid.sync();

    // ---------------- P2: passA2 (roles 0..783, rid += MB; round-2 proven 512-thr body) ----------------
    {
        int* hist = (int*)smem;              // 16384 B
        int* aux  = (int*)(smem + 16384);    // 2048 B
        int* shv  = (int*)(smem + 18432);
        for (int rid = bid; rid < NSB * 4; rid += MB) {
            __syncthreads();                 // guard LDS reuse across roles
            const int b = rid >> 2;
            const int q = rid & 3;
            const int t = tid;

            // inline bucket-base scan over gcur[0..NSB)
            int v = (t < NSB) ? min(gcur[t], SBCAP) : 0;
            aux[t] = v;
            __syncthreads();
            for (int d = 1; d < 256; d <<= 1) {
                int xv = (t >= d) ? aux[t - d] : 0;
                __syncthreads();
                if (t >= d) aux[t] += xv;
                __syncthreads();
            }
            if (t == 0) shv[0] = (b == 0) ? 0 : aux[b - 1];
            __syncthreads();
            const int gb = shv[0];
            const int cnt = min(gcur[b], SBCAP);
            const int2* base = btmp + (size_t)b * SBCAP;
            __syncthreads();                 // aux reused below

            for (int i = t; i < 4096; i += MT) hist[i] = 0;
            __syncthreads();
            for (int i = t; i < cnt; i += MT) atomicAdd(&hist[base[i].x & 4095], 1);
            __syncthreads();

            int loc[8];
            int run = 0;
#pragma unroll
            for (int j = 0; j < 8; ++j) { loc[j] = run; run += hist[t * 8 + j]; }
            aux[t] = run;
            __syncthreads();
            for (int d = 1; d < 512; d <<= 1) {
                int xv = (t >= d) ? aux[t - d] : 0;
                __syncthreads();
                if (t >= d) aux[t] += xv;
                __syncthreads();
            }
            const int tbase = aux[t] - run;
            __syncthreads();

#pragma unroll
            for (int j = 0; j < 8; ++j) {
                int bin = t * 8 + j;
                int excl = tbase + loc[j];
                int incl = excl + hist[bin];
                if ((t >> 7) == q) {
                    int gkey = (b << 12) + bin;
                    if (gkey < NBINS) off2[gkey + 1] = gb + incl;
                }
                hist[bin] = excl;
            }
            __syncthreads();

            for (int i = t; i < cnt; i += MT) {
                int2 e = base[i];
                int lb = e.x & 4095;
                if ((lb >> 10) == q) {
                    int pos = gb + atomicAdd(&hist[lb], 1);
                    packed1[pos] = e.y;
                }
            }
        }
    }
    grid.sync();

    // ---------------- P3: gemm (round-4 LDS-free swapped-operand body) ----------------
    {
        const int lane = tid & 63;
        const int wv = tid >> 6;
        const int m = lane & 15;
        const int quad = lane >> 4;

        f16x8 bf[4][4];
#pragma unroll
        for (int t = 0; t < 4; ++t) {
            const f16* wc = wbt + (size_t)(wv * 64 + t * 16 + m) * 128 + quad * 8;
#pragma unroll
            for (int kk = 0; kk < 4; ++kk)
                bf[t][kk] = *(const f16x8*)(wc + kk * 32);
        }

        int tile = bid;
        f16x8 a[4];
        if (tile < NTILES) {
            const f16* xrow = xh + (size_t)(tile * 16 + m) * 128 + quad * 8;
#pragma unroll
            for (int kk = 0; kk < 4; ++kk) a[kk] = *(const f16x8*)(xrow + kk * 32);
        }

        while (tile < NTILES) {
            const int n0 = tile * 16;
            const int next = tile + MB;

            f16x8 hv[2];
#pragma unroll
            for (int t = 0; t < 4; ++t) {
                f32x4 acc = {0.f, 0.f, 0.f, 0.f};
#pragma unroll
                for (int kk = 0; kk < 4; ++kk)
                    acc = __builtin_amdgcn_mfma_f32_16x16x32_f16(bf[t][kk], a[kk], acc, 0, 0, 0);
#pragma unroll
                for (int i = 0; i < 4; ++i)
                    hv[t >> 1][(t & 1) * 4 + i] = (f16)acc[i];
            }

            if (next < NTILES) {
                const f16* xrow = xh + (size_t)(next * 16 + m) * 128 + quad * 8;
#pragma unroll
                for (int kk = 0; kk < 4; ++kk) a[kk] = *(const f16x8*)(xrow + kk * 32);
            }

            f16* dst = dense1 + (size_t)(n0 + m) * 512 + wv * 64 + quad * 16;
            *(f16x8*)dst       = hv[0];
            *(f16x8*)(dst + 8) = hv[1];
            tile = next;
        }
    }
    grid.sync();

    // ---------------- P4: agg1 (wave/node, unroll 8) ----------------
    {
        const int lane = tid & 63;
        const int lane2 = lane * 2;
        const char* m1 = (const char*)dense1;
        const int wid = bid * 8 + (tid >> 6);
        const int nw = MB * 8;
        const float bias = bias1[lane];

        for (int n = wid; n < N_NODES; n += nw) {
            const int st = off2[n << 3];
            const int en = off2[(n << 3) + 7];
            const float hroot = (float)dense1[(size_t)n * 512 + lane];
            float add = 0.f, cur = 0.f;
            int prev_r = -1;

#define MRG(kk, vv) { \
            int r_ = (int)((kk) >> 28); \
            bool same_ = (r_ == prev_r); \
            add += same_ ? 0.f : cur; \
            cur = same_ ? fmaxf(cur, (vv)) : (vv); \
            prev_r = r_; }

            int p = st;
            for (; p + 7 < en; p += 8) {
                unsigned k0 = (unsigned)packed1[p];
                unsigned k1 = (unsigned)packed1[p + 1];
                unsigned k2 = (unsigned)packed1[p + 2];
                unsigned k3 = (unsigned)packed1[p + 3];
                unsigned k4 = (unsigned)packed1[p + 4];
                unsigned k5 = (unsigned)packed1[p + 5];
                unsigned k6 = (unsigned)packed1[p + 6];
                unsigned k7 = (unsigned)packed1[p + 7];
                float v0 = (float)*(const f16*)(m1 + (k0 & OFFM) + lane2);
                float v1 = (float)*(const f16*)(m1 + (k1 & OFFM) + lane2);
                float v2 = (float)*(const f16*)(m1 + (k2 & OFFM) + lane2);
                float v3 = (float)*(const f16*)(m1 + (k3 & OFFM) + lane2);
                float v4 = (float)*(const f16*)(m1 + (k4 & OFFM) + lane2);
                float v5 = (float)*(const f16*)(m1 + (k5 & OFFM) + lane2);
                float v6 = (float)*(const f16*)(m1 + (k6 & OFFM) + lane2);
                float v7 = (float)*(const f16*)(m1 + (k7 & OFFM) + lane2);
                MRG(k0, v0) MRG(k1, v1) MRG(k2, v2) MRG(k3, v3)
                MRG(k4, v4) MRG(k5, v5) MRG(k6, v6) MRG(k7, v7)
            }
            for (; p + 3 < en; p += 4) {
                unsigned k0 = (unsigned)packed1[p];
                unsigned k1 = (unsigned)packed1[p + 1];
                unsigned k2 = (unsigned)packed1[p + 2];
                unsigned k3 = (unsigned)packed1[p + 3];
                float v0 = (float)*(const f16*)(m1 + (k0 & OFFM) + lane2);
                float v1 = (float)*(const f16*)(m1 + (k1 & OFFM) + lane2);
                float v2 = (float)*(const f16*)(m1 + (k2 & OFFM) + lane2);
                float v3 = (float)*(const f16*)(m1 + (k3 & OFFM) + lane2);
                MRG(k0, v0) MRG(k1, v1) MRG(k2, v2) MRG(k3, v3)
            }
            for (; p < en; ++p) {
                unsigned k0 = (unsigned)packed1[p];
                float v0 = (float)*(const f16*)(m1 + (k0 & OFFM) + lane2);
                MRG(k0, v0)
            }
#undef MRG
            add += cur;

            h16[((size_t)n << 6) + lane] = (f16)fmaxf(hroot + bias + add, 0.f);
        }
    }
    grid.sync();

    // ---------------- P5: pre2 (per-16-node-tile MFMA) ----------------
    {
        const int lane = tid & 63;
        const int wv = tid >> 6;
        const int m = lane & 15;
        const int quad = lane >> 4;
        for (int nt = bid * 8 + wv; nt < NTILES; nt += MB * 8) {
            const int n0 = nt * 16;
            const f16* hrow = h16 + (size_t)(n0 + m) * 64 + quad * 8;
            const f16* wcol = w2t + (size_t)m * 64 + quad * 8;
            f32x4 acc = {0.f, 0.f, 0.f, 0.f};
            f16x8 a0 = *(const f16x8*)(hrow);
            f16x8 b0 = *(const f16x8*)(wcol);
            acc = __builtin_amdgcn_mfma_f32_16x16x32_f16(a0, b0, acc, 0, 0, 0);
            f16x8 a1 = *(const f16x8*)(hrow + 32);
            f16x8 b1 = *(const f16x8*)(wcol + 32);
            acc = __builtin_amdgcn_mfma_f32_16x16x32_f16(a1, b1, acc, 0, 0, 0);

            const float badd = (m == 14) ? bias2[0] : ((m == 15) ? bias2[1] : 0.f);
#pragma unroll
            for (int i = 0; i < 4; ++i)
                msg2[(size_t)(n0 + quad * 4 + i) * 16 + m] = acc[i] + badd;
        }
    }
    grid.sync();

    // ---------------- P6: agg2 (thread/node, unroll 8) ----------------
    {
        const char* m2 = (const char*)msg2;
        for (int n = gtid; n < N_NODES; n += MB * MT) {
            const int st = off2[n << 3];
            const int en = off2[(n << 3) + 7];
            float addx = 0.f, addy = 0.f, curx = 0.f, cury = 0.f;
            int prev_r = -1;

#define MRG2(kk, ff) { \
            int r_ = (int)((kk) >> 28); \
            bool same_ = (r_ == prev_r); \
            addx += same_ ? 0.f : curx; \
            addy += same_ ? 0.f : cury; \
            curx = same_ ? fmaxf(curx, (ff).x) : (ff).x; \
            cury = same_ ? fmaxf(cury, (ff).y) : (ff).y; \
            prev_r = r_; }

            int p = st;
            for (; p + 7 < en; p += 8) {
                unsigned k0 = (unsigned)packed1[p],     k1 = (unsigned)packed1[p + 1];
                unsigned k2 = (unsigned)packed1[p + 2], k3 = (unsigned)packed1[p + 3];
                unsigned k4 = (unsigned)packed1[p + 4], k5 = (unsigned)packed1[p + 5];
                unsigned k6 = (unsigned)packed1[p + 6], k7 = (unsigned)packed1[p + 7];
                float2 f0 = *(const float2*)(m2 + (((k0 & OFFM) >> 4) - 8));
                float2 f1 = *(const float2*)(m2 + (((k1 & OFFM) >> 4) - 8));
                float2 f2 = *(const float2*)(m2 + (((k2 & OFFM) >> 4) - 8));
                float2 f3 = *(const float2*)(m2 + (((k3 & OFFM) >> 4) - 8));
                float2 f4 = *(const float2*)(m2 + (((k4 & OFFM) >> 4) - 8));
                float2 f5 = *(const float2*)(m2 + (((k5 & OFFM) >> 4) - 8));
                float2 f6 = *(const float2*)(m2 + (((k6 & OFFM) >> 4) - 8));
                float2 f7 = *(const float2*)(m2 + (((k7 & OFFM) >> 4) - 8));
                MRG2(k0, f0) MRG2(k1, f1) MRG2(k2, f2) MRG2(k3, f3)
                MRG2(k4, f4) MRG2(k5, f5) MRG2(k6, f6) MRG2(k7, f7)
            }
            for (; p < en; ++p) {
                unsigned k0 = (unsigned)packed1[p];
                float2 f0 = *(const float2*)(m2 + (((k0 & OFFM) >> 4) - 8));
                MRG2(k0, f0)
            }
#undef MRG2

            out[(size_t)n * 2 + 0] = msg2[(size_t)n * 16 + 14] + addx + curx;
            out[(size_t)n * 2 + 1] = msg2[(size_t)n * 16 + 15] + addy + cury;
        }
    }
}

// ===================================================================================
// ===================== LEGACY FALLBACK (round-4 proven pipeline) ===================
// ===================================================================================
__global__ __launch_bounds__(256)
void k1_fused_kernel(const int* __restrict__ ei, const int* __restrict__ et,
                     int* __restrict__ gcur, int2* __restrict__ btmp,
                     const float* __restrict__ x, f16* __restrict__ xh,
                     const float* __restrict__ root1, const float* __restrict__ W1,
                     const float* __restrict__ comp2, const float* __restrict__ basis2,
                     const float* __restrict__ root2, f16* __restrict__ wbt,
                     f16* __restrict__ w2t)
{
    __shared__ int2 ent[CHUNK];
    __shared__ int lhist[NSB], lcur[NSB], gposl[NSB];
    const int bid = blockIdx.x;

    if (bid < NBLK_A1) {
        const int cbase = bid * CHUNK;
        const int cnt = min(CHUNK, N_EDGESV - cbase);

        for (int i = threadIdx.x; i < NSB; i += 256) { lhist[i] = 0; lcur[i] = 0; }
        __syncthreads();

        for (int i = threadIdx.x; i < cnt; i += 256) {
            int e = cbase + i;
            int d = ei[N_EDGESV + e];
            int s = ei[e];
            int r = et[e];
            ent[i] = make_int2((d << 3) + r, (s * 1024 + 128 + r * 128) | (r << 28));
            atomicAdd(&lhist[d >> 9], 1);
        }
        __syncthreads();

        for (int b = threadIdx.x; b < NSB; b += 256)
            gposl[b] = atomicAdd(&gcur[b], lhist[b]);
        __syncthreads();

        for (int i = threadIdx.x; i < cnt; i += 256) {
            int2 en = ent[i];
            int b = en.x >> 12;
            int off = atomicAdd(&lcur[b], 1);
            int idx = gposl[b] + off;
            if (idx < SBCAP) btmp[(size_t)b * SBCAP + idx] = en;
        }
    } else if (bid < NBLK_A1 + XH_BLOCKS) {
        for (int i = (bid - NBLK_A1) * 256 + threadIdx.x; i < XH_TOTAL;
             i += XH_BLOCKS * 256) {
            float4 v = ((const float4*)x)[i];
            f16x4 o = {(f16)v.x, (f16)v.y, (f16)v.z, (f16)v.w};
            *(f16x4*)(xh + (size_t)i * 4) = o;
        }
    } else {
        const int t0 = (bid - NBLK_A1 - XH_BLOCKS) * 256 + threadIdx.x;
        for (int idx = t0; idx < 512 * 128; idx += WB_BLOCKS * 256) {
            int p = idx >> 7, k = idx & 127;
            int lp = p & 63;
            int lc = ((lp & 15) >> 2) * 16 + ((lp >> 4) << 2) + (lp & 3);
            int col = (p & ~63) | lc;
            float v;
            if (col < 64) {
                v = root1[k * HID_CH + col];
            } else {
                int cc = col - 64, r = cc >> 6, inner = cc & 63, b = inner >> 4, j = inner & 15;
                int kb = k - b * 32;
                v = (kb >= 0 && kb < 32) ? W1[(((r * 4 + b) * 32) + kb) * 16 + j] : 0.f;
            }
            wbt[idx] = (f16)v;
        }
        for (int idx = t0; idx < 16 * 64; idx += WB_BLOCKS * 256) {
            int col = idx >> 6, k = idx & 63;
            float v;
            if (col < 14) {
                int r = col >> 1, oc = col & 1;
                v = 0.f;
                for (int b = 0; b < 4; ++b) v += comp2[r * 4 + b] * basis2[(b * 64 + k) * 2 + oc];
            } else {
                v = root2[k * 2 + (col - 14)];
            }
            w2t[idx] = (f16)v;
        }
    }
}

__global__ __launch_bounds__(512, 4)
void gemm1_kernel(const f16* __restrict__ xh, const f16* __restrict__ wbt,
                  f16* __restrict__ dense1) {
    const int lane = threadIdx.x & 63;
    const int wv = threadIdx.x >> 6;
    const int m = lane & 15;
    const int quad = lane >> 4;

    f16x8 bf[4][4];
#pragma unroll
    for (int t = 0; t < 4; ++t) {
        const f16* wc = wbt + (size_t)(wv * 64 + t * 16 + m) * 128 + quad * 8;
#pragma unroll
        for (int kk = 0; kk < 4; ++kk)
            bf[t][kk] = *(const f16x8*)(wc + kk * 32);
    }

    int tile = blockIdx.x;
    f16x8 a[4];
    if (tile < NTILES) {
        const f16* xrow = xh + (size_t)(tile * 16 + m) * 128 + quad * 8;
#pragma unroll
        for (int kk = 0; kk < 4; ++kk) a[kk] = *(const f16x8*)(xrow + kk * 32);
    }

    while (tile < NTILES) {
        const int n0 = tile * 16;
        const int next = tile + gridDim.x;

        f16x8 hv[2];
#pragma unroll
        for (int t = 0; t < 4; ++t) {
            f32x4 acc = {0.f, 0.f, 0.f, 0.f};
#pragma unroll
            for (int kk = 0; kk < 4; ++kk)
                acc = __builtin_amdgcn_mfma_f32_16x16x32_f16(bf[t][kk], a[kk], acc, 0, 0, 0);
#pragma unroll
            for (int i = 0; i < 4; ++i)
                hv[t >> 1][(t & 1) * 4 + i] = (f16)acc[i];
        }

        if (next < NTILES) {
            const f16* xrow = xh + (size_t)(next * 16 + m) * 128 + quad * 8;
#pragma unroll
            for (int kk = 0; kk < 4; ++kk) a[kk] = *(const f16x8*)(xrow + kk * 32);
        }

        f16* dst = dense1 + (size_t)(n0 + m) * 512 + wv * 64 + quad * 16;
        *(f16x8*)dst       = hv[0];
        *(f16x8*)(dst + 8) = hv[1];
        tile = next;
    }
}

__global__ __launch_bounds__(256)
void passA2_kernel(const int* __restrict__ gcur, const int2* __restrict__ btmp,
                   int* __restrict__ off2, int* __restrict__ packed1) {
    __shared__ int hist[4096];
    __shared__ int aux[256];
    __shared__ int shv[1];
    const int b = blockIdx.x >> 2;
    const int q = blockIdx.x & 3;
    const int t = threadIdx.x;

    if (blockIdx.x == 0 && t == 0) off2[0] = 0;

    int v0 = (t < NSB) ? min(gcur[t], SBCAP) : 0;
    aux[t] = v0;
    __syncthreads();
    for (int d = 1; d < 256; d <<= 1) {
        int xv = (t >= d) ? aux[t - d] : 0;
        __syncthreads();
        if (t >= d) aux[t] += xv;
        __syncthreads();
    }
    if (t == 0) shv[0] = (b == 0) ? 0 : aux[b - 1];
    __syncthreads();
    const int gb = shv[0];
    const int cnt = min(gcur[b], SBCAP);
    const int2* base = btmp + (size_t)b * SBCAP;
    __syncthreads();

    for (int i = t; i < 4096; i += 256) hist[i] = 0;
    __syncthreads();
    for (int i = t; i < cnt; i += 256) atomicAdd(&hist[base[i].x & 4095], 1);
    __syncthreads();

    int loc[16];
    int run = 0;
#pragma unroll
    for (int j = 0; j < 16; ++j) { loc[j] = run; run += hist[t * 16 + j]; }
    aux[t] = run;
    __syncthreads();
    for (int d = 1; d < 256; d <<= 1) {
        int xv = (t >= d) ? aux[t - d] : 0;
        __syncthreads();
        if (t >= d) aux[t] += xv;
        __syncthreads();
    }
    const int tbase = aux[t] - run;
    __syncthreads();

#pragma unroll
    for (int j = 0; j < 16; ++j) {
        int bin = t * 16 + j;
        int excl = tbase + loc[j];
        int incl = excl + hist[bin];
        if ((t >> 6) == q) {
            int gkey = (b << 12) + bin;
            if (gkey < NBINS) off2[gkey + 1] = gb + incl;
        }
        hist[bin] = excl;
    }
    __syncthreads();

    for (int i = t; i < cnt; i += 256) {
        int2 e = base[i];
        int lb = e.x & 4095;
        if ((lb >> 10) == q) {
            int pos = gb + atomicAdd(&hist[lb], 1);
            packed1[pos] = e.y;
        }
    }
}

__global__ __launch_bounds__(256)
void agg1_kernel(const f16* __restrict__ dense1, const float* __restrict__ bias1,
                 const int* __restrict__ off2, const int* __restrict__ packed1,
                 f16* __restrict__ h16)
{
    const int lane = threadIdx.x & 63;
    const int lane2 = lane * 2;
    const char* m1 = (const char*)dense1;
    const int wid = blockIdx.x * 4 + (threadIdx.x >> 6);
    const int nw = gridDim.x * 4;
    const float bias = bias1[lane];

    for (int n = wid; n < N_NODES; n += nw) {
        const int st = off2[n << 3];
        const int en = off2[(n << 3) + 7];
        const float hroot = (float)dense1[(size_t)n * 512 + lane];
        float add = 0.f, cur = 0.f;
        int prev_r = -1;

#define MRG(kk, vv) { \
        int r_ = (int)((kk) >> 28); \
        bool same_ = (r_ == prev_r); \
        add += same_ ? 0.f : cur; \
        cur = same_ ? fmaxf(cur, (vv)) : (vv); \
        prev_r = r_; }

        int p = st;
        for (; p + 7 < en; p += 8) {
            unsigned k0 = (unsigned)packed1[p];
            unsigned k1 = (unsigned)packed1[p + 1];
            unsigned k2 = (unsigned)packed1[p + 2];
            unsigned k3 = (unsigned)packed1[p + 3];
            unsigned k4 = (unsigned)packed1[p + 4];
            unsigned k5 = (unsigned)packed1[p + 5];
            unsigned k6 = (unsigned)packed1[p + 6];
            unsigned k7 = (unsigned)packed1[p + 7];
            float v0 = (float)*(const f16*)(m1 + (k0 & OFFM) + lane2);
            float v1 = (float)*(const f16*)(m1 + (k1 & OFFM) + lane2);
            float v2 = (float)*(const f16*)(m1 + (k2 & OFFM) + lane2);
            float v3 = (float)*(const f16*)(m1 + (k3 & OFFM) + lane2);
            float v4 = (float)*(const f16*)(m1 + (k4 & OFFM) + lane2);
            float v5 = (float)*(const f16*)(m1 + (k5 & OFFM) + lane2);
            float v6 = (float)*(const f16*)(m1 + (k6 & OFFM) + lane2);
            float v7 = (float)*(const f16*)(m1 + (k7 & OFFM) + lane2);
            MRG(k0, v0) MRG(k1, v1) MRG(k2, v2) MRG(k3, v3)
            MRG(k4, v4) MRG(k5, v5) MRG(k6, v6) MRG(k7, v7)
        }
        for (; p + 3 < en; p += 4) {
            unsigned k0 = (unsigned)packed1[p];
            unsigned k1 = (unsigned)packed1[p + 1];
            unsigned k2 = (unsigned)packed1[p + 2];
            unsigned k3 = (unsigned)packed1[p + 3];
            float v0 = (float)*(const f16*)(m1 + (k0 & OFFM) + lane2);
            float v1 = (float)*(const f16*)(m1 + (k1 & OFFM) + lane2);
            float v2 = (float)*(const f16*)(m1 + (k2 & OFFM) + lane2);
            float v3 = (float)*(const f16*)(m1 + (k3 & OFFM) + lane2);
            MRG(k0, v0) MRG(k1, v1) MRG(k2, v2) MRG(k3, v3)
        }
        for (; p < en; ++p) {
            unsigned k0 = (unsigned)packed1[p];
            float v0 = (float)*(const f16*)(m1 + (k0 & OFFM) + lane2);
            MRG(k0, v0)
        }
#undef MRG
        add += cur;

        h16[((size_t)n << 6) + lane] = (f16)fmaxf(hroot + bias + add, 0.f);
    }
}

__global__ __launch_bounds__(256)
void pre2_kernel(const f16* __restrict__ h16, const f16* __restrict__ w2t,
                 const float* __restrict__ bias2, float* __restrict__ msg2) {
    const int lane = threadIdx.x & 63;
    const int wv = threadIdx.x >> 6;
    const int nt = blockIdx.x * 4 + wv;
    if (nt >= NTILES) return;
    const int n0 = nt * 16;
    const int m = lane & 15;
    const int quad = lane >> 4;

    const f16* hrow = h16 + (size_t)(n0 + m) * 64 + quad * 8;
    const f16* wcol = w2t + (size_t)m * 64 + quad * 8;
    f32x4 acc = {0.f, 0.f, 0.f, 0.f};
    f16x8 a0 = *(const f16x8*)(hrow);
    f16x8 b0 = *(const f16x8*)(wcol);
    acc = __builtin_amdgcn_mfma_f32_16x16x32_f16(a0, b0, acc, 0, 0, 0);
    f16x8 a1 = *(const f16x8*)(hrow + 32);
    f16x8 b1 = *(const f16x8*)(wcol + 32);
    acc = __builtin_amdgcn_mfma_f32_16x16x32_f16(a1, b1, acc, 0, 0, 0);

    const float badd = (m == 14) ? bias2[0] : ((m == 15) ? bias2[1] : 0.f);
#pragma unroll
    for (int i = 0; i < 4; ++i)
        msg2[(size_t)(n0 + quad * 4 + i) * 16 + m] = acc[i] + badd;
}

__global__ __launch_bounds__(256)
void agg2_kernel(const float* __restrict__ msg2, const int* __restrict__ off2,
                 const int* __restrict__ packed1, float* __restrict__ out)
{
    const int n = blockIdx.x * blockDim.x + threadIdx.x;
    if (n >= N_NODES) return;
    const char* m2 = (const char*)msg2;
    const int st = off2[n << 3];
    const int en = off2[(n << 3) + 7];
    float addx = 0.f, addy = 0.f, curx = 0.f, cury = 0.f;
    int prev_r = -1;

#define MRG2(kk, ff) { \
    int r_ = (int)((kk) >> 28); \
    bool same_ = (r_ == prev_r); \
    addx += same_ ? 0.f : curx; \
    addy += same_ ? 0.f : cury; \
    curx = same_ ? fmaxf(curx, (ff).x) : (ff).x; \
    cury = same_ ? fmaxf(cury, (ff).y) : (ff).y; \
    prev_r = r_; }

    int p = st;
    for (; p + 7 < en; p += 8) {
        unsigned k0 = (unsigned)packed1[p],     k1 = (unsigned)packed1[p + 1];
        unsigned k2 = (unsigned)packed1[p + 2], k3 = (unsigned)packed1[p + 3];
        unsigned k4 = (unsigned)packed1[p + 4], k5 = (unsigned)packed1[p + 5];
        unsigned k6 = (unsigned)packed1[p + 6], k7 = (unsigned)packed1[p + 7];
        float2 f0 = *(const float2*)(m2 + (((k0 & OFFM) >> 4) - 8));
        float2 f1 = *(const float2*)(m2 + (((k1 & OFFM) >> 4) - 8));
        float2 f2 = *(const float2*)(m2 + (((k2 & OFFM) >> 4) - 8));
        float2 f3 = *(const float2*)(m2 + (((k3 & OFFM) >> 4) - 8));
        float2 f4 = *(const float2*)(m2 + (((k4 & OFFM) >> 4) - 8));
        float2 f5 = *(const float2*)(m2 + (((k5 & OFFM) >> 4) - 8));
        float2 f6 = *(const float2*)(m2 + (((k6 & OFFM) >> 4) - 8));
        float2 f7 = *(const float2*)(m2 + (((k7 & OFFM) >> 4) - 8));
        MRG2(k0, f0) MRG2(k1, f1) MRG2(k2, f2) MRG2(k3, f3)
        MRG2(k4, f4) MRG2(k5, f5) MRG2(k6, f6) MRG2(k7, f7)
    }
    for (; p < en; ++p) {
        unsigned k0 = (unsigned)packed1[p];
        float2 f0 = *(const float2*)(m2 + (((k0 & OFFM) >> 4) - 8));
        MRG2(k0, f0)
    }
#undef MRG2

    out[(size_t)n * 2 + 0] = msg2[(size_t)n * 16 + 14] + addx + curx;
    out[(size_t)n * 2 + 1] = msg2[(size_t)n * 16 + 15] + addy + cury;
}

extern "C" void kernel_launch(void* const* d_in, const int* in_sizes, int n_in,
                              void* d_out, int out_size, void* d_ws, size_t ws_size,
                              hipStream_t stream)
{
    const int*   ei     = (const int*)d_in[1];
    const int*   et     = (const int*)d_in[2];
    const float* x      = (const float*)d_in[0];
    const float* W1     = (const float*)d_in[3];
    const float* root1  = (const float*)d_in[4];
    const float* bias1  = (const float*)d_in[5];
    const float* comp2  = (const float*)d_in[6];
    const float* basis2 = (const float*)d_in[7];
    const float* root2  = (const float*)d_in[8];
    const float* bias2  = (const float*)d_in[9];
    float* out = (float*)d_out;

    // workspace carve-up
    char* ws = (char*)d_ws;
    size_t o = 0;
    auto carve = [&](size_t bytes) { char* p = ws + o; o += (bytes + 255) & ~(size_t)255; return p; };
    int*   off2    = (int*)carve(sizeof(int) * (NBINS + 1));
    int*   gcur    = (int*)carve(sizeof(int) * NSB);
    int2*  btmp    = (int2*)carve(sizeof(int2) * (size_t)NSB * SBCAP);           // 12.8 MB
    int*   packed1 = (int*)carve(sizeof(int) * N_EDGESV);
    f16*   xh      = (f16*)carve(sizeof(f16) * (size_t)N_NODES * IN_CH);         // 25.6 MB
    f16*   wbt     = (f16*)carve(sizeof(f16) * 512 * 128);
    f16*   w2t     = (f16*)carve(sizeof(f16) * 16 * 64);
    f16*   dense1  = (f16*)carve(sizeof(f16) * (size_t)N_NODES * 512);           // 102.4 MB
    f16*   h16     = (f16*)carve(sizeof(f16) * (size_t)N_NODES * HID_CH);        // 12.8 MB
    float* msg2    = (float*)carve(sizeof(float) * (size_t)N_NODES * 16);        //  6.4 MB

    // ---- primary path: single cooperative dispatch ----
    void* args[] = {
        (void*)&ei, (void*)&et, (void*)&x, (void*)&W1, (void*)&root1, (void*)&bias1,
        (void*)&comp2, (void*)&basis2, (void*)&root2, (void*)&bias2,
        (void*)&gcur, (void*)&btmp, (void*)&off2, (void*)&packed1,
        (void*)&xh, (void*)&wbt, (void*)&w2t, (void*)&dense1, (void*)&h16,
        (void*)&msg2, (void*)&out
    };
    hipError_t err = hipLaunchCooperativeKernel(mega_kernel, dim3(MB), dim3(MT),
                                                args, 0, stream);
    if (err == hipSuccess) return;

    // ---- fallback: proven round-4 multi-dispatch pipeline ----
    hipMemsetAsync(gcur, 0, sizeof(int) * NSB, stream);
    k1_fused_kernel<<<NBLK_A1 + XH_BLOCKS + WB_BLOCKS, 256, 0, stream>>>(
        ei, et, gcur, btmp, x, xh, root1, W1, comp2, basis2, root2, wbt, w2t);
    gemm1_kernel<<<1024, 512, 0, stream>>>(xh, wbt, dense1);
    passA2_kernel<<<NSB * 4, 256, 0, stream>>>(gcur, btmp, off2, packed1);
    agg1_kernel<<<2048, 256, 0, stream>>>(dense1, bias1, off2, packed1, h16);
    pre2_kernel<<<(NTILES + 3) / 4, 256, 0, stream>>>(h16, w2t, bias2, msg2);
    agg2_kernel<<<(N_NODES + 255) / 256, 256, 0, stream>>>(msg2, off2, packed1, out);
}

// Round 6
// 257.205 us; speedup vs baseline: 2.5836x; 2.5836x over previous
//
#include <hip/hip_runtime.h>

#define N_NODES 100000
#define N_EDGESV 1000000
#define N_REL 7
#define IN_CH 128
#define HID_CH 64
#define NBINS 800000          // (dst, rel) bins: key = d*8 + r
#define OFFM 0x0FFFFFFFu
#define NTILES 6250           // N_NODES / 16
#define NSB 196               // super-buckets: dst>>9 (512 nodes each)
#define SBCAP 8192            // mean 5102, sigma~71 -> +43 sigma margin
#define NBLK_A1 512
#define CHUNK 1954            // ceil(1e6 / 512)
#define XH_BLOCKS 2048
#define WB_BLOCKS 64
#define XH_TOTAL (N_NODES * IN_CH / 4)

typedef _Float16 f16;
typedef __attribute__((ext_vector_type(8))) _Float16 f16x8;
typedef __attribute__((ext_vector_type(4))) _Float16 f16x4;
typedef __attribute__((ext_vector_type(4))) float f32x4;

// ================= K1: fused passA1 | xh | wbuild (independent roles, 256 thr) =================
// wbuild writes wbt with the t<->quad row PERMUTATION (round-1/4 verified): physical row p
// holds logical col (p&~63)|perm(p&63), perm(l) = ((l&15)>>2)*16 + ((l>>4)<<2) + (l&3).
__global__ __launch_bounds__(256)
void k1_fused_kernel(const int* __restrict__ ei, const int* __restrict__ et,
                     int* __restrict__ gcur, int2* __restrict__ btmp,
                     const float* __restrict__ x, f16* __restrict__ xh,
                     const float* __restrict__ root1, const float* __restrict__ W1,
                     const float* __restrict__ comp2, const float* __restrict__ basis2,
                     const float* __restrict__ root2, f16* __restrict__ wbt,
                     f16* __restrict__ w2t)
{
    __shared__ int2 ent[CHUNK];          // 15632 B (passA1 role only)
    __shared__ int lhist[NSB], lcur[NSB], gposl[NSB];
    const int bid = blockIdx.x;

    if (bid < NBLK_A1) {
        // ---- role: passA1 (LDS-binned radix scatter by dst>>9) ----
        const int cbase = bid * CHUNK;
        const int cnt = min(CHUNK, N_EDGESV - cbase);

        for (int i = threadIdx.x; i < NSB; i += 256) { lhist[i] = 0; lcur[i] = 0; }
        __syncthreads();

        for (int i = threadIdx.x; i < cnt; i += 256) {
            int e = cbase + i;
            int d = ei[N_EDGESV + e];
            int s = ei[e];
            int r = et[e];
            ent[i] = make_int2((d << 3) + r, (s * 1024 + 128 + r * 128) | (r << 28));
            atomicAdd(&lhist[d >> 9], 1);
        }
        __syncthreads();

        for (int b = threadIdx.x; b < NSB; b += 256)
            gposl[b] = atomicAdd(&gcur[b], lhist[b]);
        __syncthreads();

        for (int i = threadIdx.x; i < cnt; i += 256) {
            int2 en = ent[i];
            int b = en.x >> 12;
            int off = atomicAdd(&lcur[b], 1);
            int idx = gposl[b] + off;
            if (idx < SBCAP) btmp[(size_t)b * SBCAP + idx] = en;
        }
    } else if (bid < NBLK_A1 + XH_BLOCKS) {
        // ---- role: xh (x fp32 -> fp16) ----
        for (int i = (bid - NBLK_A1) * 256 + threadIdx.x; i < XH_TOTAL;
             i += XH_BLOCKS * 256) {
            float4 v = ((const float4*)x)[i];
            f16x4 o = {(f16)v.x, (f16)v.y, (f16)v.z, (f16)v.w};
            *(f16x4*)(xh + (size_t)i * 4) = o;
        }
    } else {
        // ---- role: wbuild (Wb_t[512][128] permuted + W2_t[16][64]) ----
        const int t0 = (bid - NBLK_A1 - XH_BLOCKS) * 256 + threadIdx.x;
        for (int idx = t0; idx < 512 * 128; idx += WB_BLOCKS * 256) {
            int p = idx >> 7, k = idx & 127;
            int lp = p & 63;
            int lc = ((lp & 15) >> 2) * 16 + ((lp >> 4) << 2) + (lp & 3);
            int col = (p & ~63) | lc;               // logical output column
            float v;
            if (col < 64) {
                v = root1[k * HID_CH + col];
            } else {
                int cc = col - 64, r = cc >> 6, inner = cc & 63, b = inner >> 4, j = inner & 15;
                int kb = k - b * 32;
                v = (kb >= 0 && kb < 32) ? W1[(((r * 4 + b) * 32) + kb) * 16 + j] : 0.f;
            }
            wbt[idx] = (f16)v;
        }
        for (int idx = t0; idx < 16 * 64; idx += WB_BLOCKS * 256) {
            int col = idx >> 6, k = idx & 63;
            float v;
            if (col < 14) {
                int r = col >> 1, oc = col & 1;
                v = 0.f;
                for (int b = 0; b < 4; ++b) v += comp2[r * 4 + b] * basis2[(b * 64 + k) * 2 + oc];
            } else {
                v = root2[k * 2 + (col - 14)];
            }
            w2t[idx] = (f16)v;
        }
    }
}

// ========== gemm1 (MFMA, LDS-free, barrier-free; round-4 proven 49us) ==========
__global__ __launch_bounds__(512, 4)
void gemm1_kernel(const f16* __restrict__ xh, const f16* __restrict__ wbt,
                  f16* __restrict__ dense1) {
    const int lane = threadIdx.x & 63;
    const int wv = threadIdx.x >> 6;
    const int m = lane & 15;
    const int quad = lane >> 4;

    f16x8 bf[4][4];
#pragma unroll
    for (int t = 0; t < 4; ++t) {
        const f16* wc = wbt + (size_t)(wv * 64 + t * 16 + m) * 128 + quad * 8;
#pragma unroll
        for (int kk = 0; kk < 4; ++kk)
            bf[t][kk] = *(const f16x8*)(wc + kk * 32);
    }

    int tile = blockIdx.x;
    f16x8 a[4];
    if (tile < NTILES) {
        const f16* xrow = xh + (size_t)(tile * 16 + m) * 128 + quad * 8;
#pragma unroll
        for (int kk = 0; kk < 4; ++kk) a[kk] = *(const f16x8*)(xrow + kk * 32);
    }

    while (tile < NTILES) {
        const int n0 = tile * 16;
        const int next = tile + gridDim.x;

        f16x8 hv[2];
#pragma unroll
        for (int t = 0; t < 4; ++t) {
            f32x4 acc = {0.f, 0.f, 0.f, 0.f};
#pragma unroll
            for (int kk = 0; kk < 4; ++kk)
                acc = __builtin_amdgcn_mfma_f32_16x16x32_f16(bf[t][kk], a[kk], acc, 0, 0, 0);
#pragma unroll
            for (int i = 0; i < 4; ++i)
                hv[t >> 1][(t & 1) * 4 + i] = (f16)acc[i];
        }

        if (next < NTILES) {  // prefetch next A (WAR on a[]: safe after MFMA issue)
            const f16* xrow = xh + (size_t)(next * 16 + m) * 128 + quad * 8;
#pragma unroll
            for (int kk = 0; kk < 4; ++kk) a[kk] = *(const f16x8*)(xrow + kk * 32);
        }

        f16* dst = dense1 + (size_t)(n0 + m) * 512 + wv * 64 + quad * 16;
        *(f16x8*)dst       = hv[0];
        *(f16x8*)(dst + 8) = hv[1];
        tile = next;
    }
}

// ========== passA2: 256 thr, bucketscan INLINED (round-3 proven) ==========
__global__ __launch_bounds__(256)
void passA2_kernel(const int* __restrict__ gcur, const int2* __restrict__ btmp,
                   int* __restrict__ off2, int* __restrict__ packed1) {
    __shared__ int hist[4096];  // 16 KB: bucket-local bins (d&511)*8+r
    __shared__ int aux[256];
    __shared__ int shv[1];
    const int b = blockIdx.x >> 2;
    const int q = blockIdx.x & 3;
    const int t = threadIdx.x;

    if (blockIdx.x == 0 && t == 0) off2[0] = 0;

    // phase 0: inline bucket-base scan over gcur[0..NSB)
    int v0 = (t < NSB) ? min(gcur[t], SBCAP) : 0;
    aux[t] = v0;
    __syncthreads();
    for (int d = 1; d < 256; d <<= 1) {
        int xv = (t >= d) ? aux[t - d] : 0;
        __syncthreads();
        if (t >= d) aux[t] += xv;
        __syncthreads();
    }
    if (t == 0) shv[0] = (b == 0) ? 0 : aux[b - 1];   // exclusive base
    __syncthreads();
    const int gb = shv[0];
    const int cnt = min(gcur[b], SBCAP);
    const int2* base = btmp + (size_t)b * SBCAP;
    __syncthreads();                                  // aux reused below

    // phase 1: bucket-local histogram
    for (int i = t; i < 4096; i += 256) hist[i] = 0;
    __syncthreads();
    for (int i = t; i < cnt; i += 256) atomicAdd(&hist[base[i].x & 4095], 1);
    __syncthreads();

    // phase 2: block-wide exclusive scan over 4096 bins (16 bins/thread)
    int loc[16];
    int run = 0;
#pragma unroll
    for (int j = 0; j < 16; ++j) { loc[j] = run; run += hist[t * 16 + j]; }
    aux[t] = run;
    __syncthreads();
    for (int d = 1; d < 256; d <<= 1) {
        int xv = (t >= d) ? aux[t - d] : 0;
        __syncthreads();
        if (t >= d) aux[t] += xv;
        __syncthreads();
    }
    const int tbase = aux[t] - run;
    __syncthreads();

#pragma unroll
    for (int j = 0; j < 16; ++j) {
        int bin = t * 16 + j;
        int excl = tbase + loc[j];
        int incl = excl + hist[bin];            // read before overwrite (same bin)
        if ((t >> 6) == q) {                    // my quarter's bins only
            int gkey = (b << 12) + bin;
            if (gkey < NBINS) off2[gkey + 1] = gb + incl;
        }
        hist[bin] = excl;                       // becomes bucket-relative cursor
    }
    __syncthreads();

    for (int i = t; i < cnt; i += 256) {        // place my quarter's edges
        int2 e = base[i];
        int lb = e.x & 4095;
        if ((lb >> 10) == q) {
            int pos = gb + atomicAdd(&hist[lb], 1);
            packed1[pos] = e.y;
        }
    }
}

// ========== agg1+pre2 FUSED: wave/node; after computing h row (f32/lane), the wave
// computes msg2[n][16] = h @ W2 in-wave (LDS broadcast + 16 FMA + 2 shfl_xor).
// h16 array ELIMINATED (pre2's only consumer was msg2); msg2 uses unrounded f32 h
// -> strictly closer to reference than the old f16 round-trip. ==========
__global__ __launch_bounds__(256)
void agg1_kernel(const f16* __restrict__ dense1, const float* __restrict__ bias1,
                 const float* __restrict__ bias2, const f16* __restrict__ w2t,
                 const int* __restrict__ off2, const int* __restrict__ packed1,
                 float* __restrict__ msg2)
{
    __shared__ float hbuf[4][64];
    const int lane = threadIdx.x & 63;
    const int lane2 = lane * 2;
    const int wv = threadIdx.x >> 6;
    const char* m1 = (const char*)dense1;
    const int wid = blockIdx.x * 4 + wv;
    const int nw = gridDim.x * 4;
    const float bias = bias1[lane];

    // per-lane W2 slice: lane (kq, c) holds w2t[c][kq*16 .. +16) as f32
    const int c = lane & 15;
    const int kq = lane >> 4;
    float w2v[16];
#pragma unroll
    for (int j = 0; j < 16; ++j) w2v[j] = (float)w2t[c * 64 + kq * 16 + j];
    const float badd = (c == 14) ? bias2[0] : ((c == 15) ? bias2[1] : 0.f);

    for (int n = wid; n < N_NODES; n += nw) {
        const int st = off2[n << 3];
        const int en = off2[(n << 3) + 7];
        const float hroot = (float)dense1[(size_t)n * 512 + lane];  // issue early
        float add = 0.f, cur = 0.f;
        int prev_r = -1;

#define MRG(kk, vv) { \
        int r_ = (int)((kk) >> 28); \
        bool same_ = (r_ == prev_r); \
        add += same_ ? 0.f : cur; \
        cur = same_ ? fmaxf(cur, (vv)) : (vv); \
        prev_r = r_; }

        int p = st;
        for (; p + 7 < en; p += 8) {
            unsigned k0 = (unsigned)packed1[p];
            unsigned k1 = (unsigned)packed1[p + 1];
            unsigned k2 = (unsigned)packed1[p + 2];
            unsigned k3 = (unsigned)packed1[p + 3];
            unsigned k4 = (unsigned)packed1[p + 4];
            unsigned k5 = (unsigned)packed1[p + 5];
            unsigned k6 = (unsigned)packed1[p + 6];
            unsigned k7 = (unsigned)packed1[p + 7];
            float v0 = (float)*(const f16*)(m1 + (k0 & OFFM) + lane2);
            float v1 = (float)*(const f16*)(m1 + (k1 & OFFM) + lane2);
            float v2 = (float)*(const f16*)(m1 + (k2 & OFFM) + lane2);
            float v3 = (float)*(const f16*)(m1 + (k3 & OFFM) + lane2);
            float v4 = (float)*(const f16*)(m1 + (k4 & OFFM) + lane2);
            float v5 = (float)*(const f16*)(m1 + (k5 & OFFM) + lane2);
            float v6 = (float)*(const f16*)(m1 + (k6 & OFFM) + lane2);
            float v7 = (float)*(const f16*)(m1 + (k7 & OFFM) + lane2);
            MRG(k0, v0) MRG(k1, v1) MRG(k2, v2) MRG(k3, v3)
            MRG(k4, v4) MRG(k5, v5) MRG(k6, v6) MRG(k7, v7)
        }
        for (; p + 3 < en; p += 4) {
            unsigned k0 = (unsigned)packed1[p];
            unsigned k1 = (unsigned)packed1[p + 1];
            unsigned k2 = (unsigned)packed1[p + 2];
            unsigned k3 = (unsigned)packed1[p + 3];
            float v0 = (float)*(const f16*)(m1 + (k0 & OFFM) + lane2);
            float v1 = (float)*(const f16*)(m1 + (k1 & OFFM) + lane2);
            float v2 = (float)*(const f16*)(m1 + (k2 & OFFM) + lane2);
            float v3 = (float)*(const f16*)(m1 + (k3 & OFFM) + lane2);
            MRG(k0, v0) MRG(k1, v1) MRG(k2, v2) MRG(k3, v3)
        }
        for (; p < en; ++p) {
            unsigned k0 = (unsigned)packed1[p];
            float v0 = (float)*(const f16*)(m1 + (k0 & OFFM) + lane2);
            MRG(k0, v0)
        }
#undef MRG
        add += cur;

        const float hval = fmaxf(hroot + bias + add, 0.f);  // final layer-1 h (f32)

        // ---- fused pre2: msg2[n][c] = sum_k h[k] * W2[k][c] (+bias2 on 14/15) ----
        hbuf[wv][lane] = hval;               // intra-wave LDS broadcast (in-order DS)
        float part = 0.f;
#pragma unroll
        for (int j = 0; j < 16; ++j) part += hbuf[wv][kq * 16 + j] * w2v[j];
        part += __shfl_xor(part, 16);
        part += __shfl_xor(part, 32);
        if (lane < 16) msg2[(size_t)n * 16 + c] = part + badd;
    }
}

// ========== agg2: thread/node; merged edge loop, unroll 8 (unchanged) ==========
__global__ __launch_bounds__(256)
void agg2_kernel(const float* __restrict__ msg2, const int* __restrict__ off2,
                 const int* __restrict__ packed1, float* __restrict__ out)
{
    const int n = blockIdx.x * blockDim.x + threadIdx.x;
    if (n >= N_NODES) return;
    const char* m2 = (const char*)msg2;
    const int st = off2[n << 3];
    const int en = off2[(n << 3) + 7];
    float addx = 0.f, addy = 0.f, curx = 0.f, cury = 0.f;
    int prev_r = -1;

#define MRG2(kk, ff) { \
    int r_ = (int)((kk) >> 28); \
    bool same_ = (r_ == prev_r); \
    addx += same_ ? 0.f : curx; \
    addy += same_ ? 0.f : cury; \
    curx = same_ ? fmaxf(curx, (ff).x) : (ff).x; \
    cury = same_ ? fmaxf(cury, (ff).y) : (ff).y; \
    prev_r = r_; }

    int p = st;
    for (; p + 7 < en; p += 8) {
        unsigned k0 = (unsigned)packed1[p],     k1 = (unsigned)packed1[p + 1];
        unsigned k2 = (unsigned)packed1[p + 2], k3 = (unsigned)packed1[p + 3];
        unsigned k4 = (unsigned)packed1[p + 4], k5 = (unsigned)packed1[p + 5];
        unsigned k6 = (unsigned)packed1[p + 6], k7 = (unsigned)packed1[p + 7];
        float2 f0 = *(const float2*)(m2 + (((k0 & OFFM) >> 4) - 8));
        float2 f1 = *(const float2*)(m2 + (((k1 & OFFM) >> 4) - 8));
        float2 f2 = *(const float2*)(m2 + (((k2 & OFFM) >> 4) - 8));
        float2 f3 = *(const float2*)(m2 + (((k3 & OFFM) >> 4) - 8));
        float2 f4 = *(const float2*)(m2 + (((k4 & OFFM) >> 4) - 8));
        float2 f5 = *(const float2*)(m2 + (((k5 & OFFM) >> 4) - 8));
        float2 f6 = *(const float2*)(m2 + (((k6 & OFFM) >> 4) - 8));
        float2 f7 = *(const float2*)(m2 + (((k7 & OFFM) >> 4) - 8));
        MRG2(k0, f0) MRG2(k1, f1) MRG2(k2, f2) MRG2(k3, f3)
        MRG2(k4, f4) MRG2(k5, f5) MRG2(k6, f6) MRG2(k7, f7)
    }
    for (; p < en; ++p) {
        unsigned k0 = (unsigned)packed1[p];
        float2 f0 = *(const float2*)(m2 + (((k0 & OFFM) >> 4) - 8));
        MRG2(k0, f0)
    }
#undef MRG2

    out[(size_t)n * 2 + 0] = msg2[(size_t)n * 16 + 14] + addx + curx;
    out[(size_t)n * 2 + 1] = msg2[(size_t)n * 16 + 15] + addy + cury;
}

extern "C" void kernel_launch(void* const* d_in, const int* in_sizes, int n_in,
                              void* d_out, int out_size, void* d_ws, size_t ws_size,
                              hipStream_t stream)
{
    const float* x      = (const float*)d_in[0];
    const int*   ei     = (const int*)d_in[1];
    const int*   et     = (const int*)d_in[2];
    const float* W1     = (const float*)d_in[3];
    const float* root1  = (const float*)d_in[4];
    const float* bias1  = (const float*)d_in[5];
    const float* comp2  = (const float*)d_in[6];
    const float* basis2 = (const float*)d_in[7];
    const float* root2  = (const float*)d_in[8];
    const float* bias2  = (const float*)d_in[9];
    float* out = (float*)d_out;

    // workspace carve-up
    char* ws = (char*)d_ws;
    size_t o = 0;
    auto carve = [&](size_t bytes) { char* p = ws + o; o += (bytes + 255) & ~(size_t)255; return p; };
    int*   off2    = (int*)carve(sizeof(int) * (NBINS + 1));
    int*   gcur    = (int*)carve(sizeof(int) * NSB);
    int2*  btmp    = (int2*)carve(sizeof(int2) * (size_t)NSB * SBCAP);           // 12.8 MB
    int*   packed1 = (int*)carve(sizeof(int) * N_EDGESV);
    f16*   xh      = (f16*)carve(sizeof(f16) * (size_t)N_NODES * IN_CH);         // 25.6 MB
    f16*   wbt     = (f16*)carve(sizeof(f16) * 512 * 128);
    f16*   w2t     = (f16*)carve(sizeof(f16) * 16 * 64);
    f16*   dense1  = (f16*)carve(sizeof(f16) * (size_t)N_NODES * 512);           // 102.4 MB
    float* msg2    = (float*)carve(sizeof(float) * (size_t)N_NODES * 16);        //  6.4 MB

    hipMemsetAsync(gcur, 0, sizeof(int) * NSB, stream);

    // K1: passA1 | xh | wbuild (independent roles)
    k1_fused_kernel<<<NBLK_A1 + XH_BLOCKS + WB_BLOCKS, 256, 0, stream>>>(
        ei, et, gcur, btmp, x, xh, root1, W1, comp2, basis2, root2, wbt, w2t);

    // dense precompute (round-4 proven LDS-free swapped-operand MFMA)
    gemm1_kernel<<<1024, 512, 0, stream>>>(xh, wbt, dense1);

    // CSR finalize (bucketscan inlined)
    passA2_kernel<<<NSB * 4, 256, 0, stream>>>(gcur, btmp, off2, packed1);

    // layer-1 aggregation + fused layer-2 message precompute (pre2 dispatch eliminated)
    agg1_kernel<<<2048, 256, 0, stream>>>(dense1, bias1, bias2, w2t, off2, packed1, msg2);

    // layer-2 aggregation
    agg2_kernel<<<(N_NODES + 255) / 256, 256, 0, stream>>>(msg2, off2, packed1, out);
}